// Round 7
// baseline (390.731 us; speedup 1.0000x reference)
//
#include <hip/hip_runtime.h>

#define NB 8
#define TT 8192
#define NN 256
#define BT (NB*TT)        // 65536 rows total
#define CH 64             // chunk length (scan semantics, == 2 subtiles)
#define SUB 32            // subtile rows (GEMM M-tile, LDS-resident)
#define NCHUNK (BT/CH)    // 1024
#define GPB (TT/CH)       // 128 chunks per sequence

typedef float f4 __attribute__((ext_vector_type(4)));
typedef unsigned u4 __attribute__((ext_vector_type(4)));
typedef short b8 __attribute__((ext_vector_type(8)));

static __device__ __forceinline__ ushort f2bf(float f) {
  union { float f; unsigned u; } v; v.f = f;
  return (ushort)((v.u + 0x7fffu + ((v.u >> 16) & 1u)) >> 16);  // RNE
}
static __device__ __forceinline__ float bf2f(ushort h) {
  union { unsigned u; float f; } v; v.u = ((unsigned)h) << 16; return v.f;
}

// ---------------- setup: params + bf16 weight copies (VERBATIM R3) ----------------
__global__ void k_setup(const float* __restrict__ nu_log, const float* __restrict__ theta_log,
                        const float* __restrict__ gamma_log,
                        const float* __restrict__ B_re, const float* __restrict__ B_im,
                        const float* __restrict__ C_re, const float* __restrict__ C_im,
                        float2* __restrict__ Lc, float2* __restrict__ LCH,
                        ushort* __restrict__ BnRe, ushort* __restrict__ BnIm,
                        ushort* __restrict__ CRe, ushort* __restrict__ CIm) {
  int bid = blockIdx.x, tid = threadIdx.x;
  if (bid < NN) {
    int m = bid, n = tid;
    float g = expf(gamma_log[m]);
    int idx = m * NN + n;
    BnRe[idx] = f2bf(B_re[idx] * g);
    BnIm[idx] = f2bf(B_im[idx] * g);
    CRe[idx]  = f2bf(C_re[idx]);
    CIm[idx]  = f2bf(-C_im[idx]);   // pre-negated so GEMM2 is pure accumulate
  } else {
    int m = tid;
    float Lmod = expf(-expf(nu_log[m]));
    float th = expf(theta_log[m]);
    float lre = Lmod * cosf(th), lim = Lmod * sinf(th);
    Lc[m] = make_float2(lre, lim);
    float pr = 1.f, pi = 0.f;
    for (int k = 0; k < CH; ++k) {
      float npr = pr * lre - pi * lim;
      pi = pr * lim + pi * lre;
      pr = npr;
    }
    LCH[m] = make_float2(pr, pi);   // L^CH
  }
}

// ---- GEMM1 subtile (32 rows x 256 ch) into swizzled packed-u32 LDS ----
static __device__ __forceinline__ void gemm1_sub(const float* __restrict__ x,
                                                 const ushort* __restrict__ BnRe,
                                                 const ushort* __restrict__ BnIm,
                                                 char* lds, size_t tbase, int tid) {
  int lane = tid & 63, wid = tid >> 6;
  int lr = lane & 15, lg = lane >> 4;
  int mq = wid * 64;

  f4 accRe[2][4], accIm[2][4];
  for (int i = 0; i < 2; ++i)
    for (int j = 0; j < 4; ++j) { accRe[i][j] = (f4)0.f; accIm[i][j] = (f4)0.f; }

  for (int ks = 0; ks < 8; ++ks) {
    int k0 = ks * 32 + lg * 8;
    b8 a[2];
    for (int mf = 0; mf < 2; ++mf) {
      const float* px = x + (tbase + mf * 16 + lr) * NN + k0;
      f4 x0 = *(const f4*)px;
      f4 x1 = *(const f4*)(px + 4);
      b8 t;
      t[0] = (short)f2bf(x0[0]); t[1] = (short)f2bf(x0[1]);
      t[2] = (short)f2bf(x0[2]); t[3] = (short)f2bf(x0[3]);
      t[4] = (short)f2bf(x1[0]); t[5] = (short)f2bf(x1[1]);
      t[6] = (short)f2bf(x1[2]); t[7] = (short)f2bf(x1[3]);
      a[mf] = t;
    }
    for (int nf = 0; nf < 4; ++nf) {
      int mrow = mq + nf * 16 + lr;
      b8 br = *(const b8*)(BnRe + (size_t)mrow * NN + k0);
      b8 bi = *(const b8*)(BnIm + (size_t)mrow * NN + k0);
      for (int mf = 0; mf < 2; ++mf) {
        accRe[mf][nf] = __builtin_amdgcn_mfma_f32_16x16x32_bf16(a[mf], br, accRe[mf][nf], 0, 0, 0);
        accIm[mf][nf] = __builtin_amdgcn_mfma_f32_16x16x32_bf16(a[mf], bi, accIm[mf][nf], 0, 0, 0);
      }
    }
  }
  for (int mf = 0; mf < 2; ++mf)
    for (int nf = 0; nf < 4; ++nf)
      for (int r = 0; r < 4; ++r) {
        int row = mf * 16 + lg * 4 + r;          // local row 0..31
        int col = mq + nf * 16 + lr;
        unsigned p = (unsigned)f2bf(accRe[mf][nf][r]) | ((unsigned)f2bf(accIm[mf][nf][r]) << 16);
        int off = row * 1024 + ((col * 4) ^ ((row & 7) << 4));
        *(unsigned*)(lds + off) = p;
      }
}

// ---------------- K1: 2x(subtile GEMM1 + local scan) -> carry -------------
__global__ __launch_bounds__(256) void k_carry(const float* __restrict__ x,
                                               const ushort* __restrict__ BnRe,
                                               const ushort* __restrict__ BnIm,
                                               const float2* __restrict__ Lc,
                                               float2* __restrict__ carry) {
  __shared__ char lds[SUB * 1024];
  int cid = blockIdx.x, tid = threadIdx.x;
  int c = tid;
  float2 L = Lc[c];
  float hr = 0.f, hi = 0.f;
  for (int sub = 0; sub < 2; ++sub) {
    __syncthreads();   // protect prior subtile's scan reads before overwrite
    gemm1_sub(x, BnRe, BnIm, lds, (size_t)cid * CH + sub * SUB, tid);
    __syncthreads();
    for (int k = 0; k < SUB; ++k) {
      int off = k * 1024 + ((c * 4) ^ ((k & 7) << 4));
      unsigned u = *(const unsigned*)(lds + off);
      float ur = bf2f((ushort)(u & 0xffffu)), ui = bf2f((ushort)(u >> 16));
      float nr = L.x * hr - L.y * hi + ur;
      hi = L.x * hi + L.y * hr + ui;
      hr = nr;
    }
  }
  carry[(size_t)cid * NN + c] = make_float2(hr, hi);
}

// ---------------- K2: scan carries across chunks, in place (VERBATIM R3) ----
__global__ void k_seed(float2* __restrict__ carrySeed, const float2* __restrict__ LCH) {
  int b = blockIdx.x, m = threadIdx.x;
  float2 LC = LCH[m];
  float hr = 0.f, hi = 0.f;
  for (int g = 0; g < GPB; ++g) {
    size_t idx = ((size_t)b * GPB + g) * NN + m;
    float2 c = carrySeed[idx];
    carrySeed[idx] = make_float2(hr, hi);
    float nr = LC.x * hr - LC.y * hi + c.x;
    hi = LC.x * hi + LC.y * hr + c.y;
    hr = nr;
  }
}

// ---------------- K3: 2x(subtile GEMM1 -> seeded scan -> GEMM2) -> out ----
__global__ __launch_bounds__(256) void k_out(const float* __restrict__ x,
                                             const ushort* __restrict__ BnRe,
                                             const ushort* __restrict__ BnIm,
                                             const float2* __restrict__ Lc,
                                             const float2* __restrict__ seed,
                                             const ushort* __restrict__ CRe,
                                             const ushort* __restrict__ CIm,
                                             float* __restrict__ out) {
  __shared__ char lds[SUB * 1024];
  int cid = blockIdx.x, tid = threadIdx.x;
  int lane = tid & 63, wid = tid >> 6;
  int lr = lane & 15, lg = lane >> 4;
  int mq = wid * 64;

  float2 L = Lc[tid];
  float2 s = seed[(size_t)cid * NN + tid];
  float hr = s.x, hi = s.y;

  for (int sub = 0; sub < 2; ++sub) {
    size_t rowbase = (size_t)cid * CH + sub * SUB;
    __syncthreads();   // protect prior subtile's GEMM2 reads before overwrite
    gemm1_sub(x, BnRe, BnIm, lds, rowbase, tid);
    __syncthreads();

    { // seeded scan, in place (packed Bu -> packed h)
      int c = tid;
      for (int k = 0; k < SUB; ++k) {
        int off = k * 1024 + ((c * 4) ^ ((k & 7) << 4));
        unsigned u = *(const unsigned*)(lds + off);
        float ur = bf2f((ushort)(u & 0xffffu)), ui = bf2f((ushort)(u >> 16));
        float nr = L.x * hr - L.y * hi + ur;
        hi = L.x * hi + L.y * hr + ui;
        hr = nr;
        *(unsigned*)(lds + off) = (unsigned)f2bf(hr) | ((unsigned)f2bf(hi) << 16);
      }
    }
    __syncthreads();

    // GEMM2 on this subtile (R3 verbatim, mf<2)
    f4 acc[2][4];
    for (int i = 0; i < 2; ++i)
      for (int j = 0; j < 4; ++j) acc[i][j] = (f4)0.f;

    for (int ks = 0; ks < 8; ++ks) {
      int k0 = ks * 32 + lg * 8;
      b8 ar[2], ai[2];
      for (int mf = 0; mf < 2; ++mf) {
        int row = mf * 16 + lr;
        int m4 = (row & 7) << 4;
        const char* base = lds + row * 1024;
        u4 p0 = *(const u4*)(base + ((k0 * 4) ^ m4));
        u4 p1 = *(const u4*)(base + ((k0 * 4 + 16) ^ m4));
        b8 tr, ti;
        tr[0] = (short)(p0[0] & 0xffffu); ti[0] = (short)(p0[0] >> 16);
        tr[1] = (short)(p0[1] & 0xffffu); ti[1] = (short)(p0[1] >> 16);
        tr[2] = (short)(p0[2] & 0xffffu); ti[2] = (short)(p0[2] >> 16);
        tr[3] = (short)(p0[3] & 0xffffu); ti[3] = (short)(p0[3] >> 16);
        tr[4] = (short)(p1[0] & 0xffffu); ti[4] = (short)(p1[0] >> 16);
        tr[5] = (short)(p1[1] & 0xffffu); ti[5] = (short)(p1[1] >> 16);
        tr[6] = (short)(p1[2] & 0xffffu); ti[6] = (short)(p1[2] >> 16);
        tr[7] = (short)(p1[3] & 0xffffu); ti[7] = (short)(p1[3] >> 16);
        ar[mf] = tr; ai[mf] = ti;
      }
      for (int nf = 0; nf < 4; ++nf) {
        int m = mq + nf * 16 + lr;
        b8 cr = *(const b8*)(CRe + (size_t)m * NN + k0);
        b8 ci = *(const b8*)(CIm + (size_t)m * NN + k0);
        for (int mf = 0; mf < 2; ++mf) {
          acc[mf][nf] = __builtin_amdgcn_mfma_f32_16x16x32_bf16(ar[mf], cr, acc[mf][nf], 0, 0, 0);
          acc[mf][nf] = __builtin_amdgcn_mfma_f32_16x16x32_bf16(ai[mf], ci, acc[mf][nf], 0, 0, 0);
        }
      }
    }
    for (int mf = 0; mf < 2; ++mf)
      for (int nf = 0; nf < 4; ++nf)
        for (int r = 0; r < 4; ++r) {
          size_t t = rowbase + mf * 16 + lg * 4 + r;
          out[t * NN + mq + nf * 16 + lr] = acc[mf][nf][r];
        }
  }
}

extern "C" void kernel_launch(void* const* d_in, const int* in_sizes, int n_in,
                              void* d_out, int out_size, void* d_ws, size_t ws_size,
                              hipStream_t stream) {
  const float* x         = (const float*)d_in[0];
  const float* nu_log    = (const float*)d_in[1];
  const float* theta_log = (const float*)d_in[2];
  const float* gamma_log = (const float*)d_in[3];
  const float* B_re      = (const float*)d_in[4];
  const float* B_im      = (const float*)d_in[5];
  const float* C_re      = (const float*)d_in[6];
  const float* C_im      = (const float*)d_in[7];
  float* out = (float*)d_out;

  // d_ws usage: 2,625,536 bytes — VERBATIM the R3 layout that passed.
  char* ws = (char*)d_ws;
  float2*  carrySeed = (float2*)(ws + 0);        // 1024*256*8 = 2,097,152
  float2*  Lc   = (float2*)(ws + 2097152);       // 2,048
  float2*  LCH  = (float2*)(ws + 2099200);       // 2,048
  ushort*  BnRe = (ushort*)(ws + 2101248);       // 131,072
  ushort*  BnIm = (ushort*)(ws + 2232320);       // 131,072
  ushort*  CRe  = (ushort*)(ws + 2363392);       // 131,072
  ushort*  CIm  = (ushort*)(ws + 2494464);       // 131,072  (end 2,625,536)

  hipLaunchKernelGGL(k_setup, dim3(NN + 1), dim3(NN), 0, stream,
                     nu_log, theta_log, gamma_log, B_re, B_im, C_re, C_im,
                     Lc, LCH, BnRe, BnIm, CRe, CIm);
  hipLaunchKernelGGL(k_carry, dim3(NCHUNK), dim3(256), 0, stream,
                     x, BnRe, BnIm, Lc, carrySeed);
  hipLaunchKernelGGL(k_seed, dim3(NB), dim3(NN), 0, stream, carrySeed, LCH);
  hipLaunchKernelGGL(k_out, dim3(NCHUNK), dim3(256), 0, stream,
                     x, BnRe, BnIm, Lc, carrySeed, CRe, CIm, out);
}

// Round 9
// 210.741 us; speedup vs baseline: 1.8541x; 1.8541x over previous
//
#include <hip/hip_runtime.h>

#define NB 8
#define TT 8192
#define NN 256
#define BT (NB*TT)        // 65536 rows total
#define CH 64             // chunk length (== GEMM M-tile)
#define NCHUNK (BT/CH)    // 1024
#define GPB (TT/CH)       // 128 chunks per sequence

typedef float f4 __attribute__((ext_vector_type(4)));
typedef unsigned u4 __attribute__((ext_vector_type(4)));
typedef short b8 __attribute__((ext_vector_type(8)));

static __device__ __forceinline__ ushort f2bf(float f) {
  union { float f; unsigned u; } v; v.f = f;
  return (ushort)((v.u + 0x7fffu + ((v.u >> 16) & 1u)) >> 16);  // RNE
}
static __device__ __forceinline__ float bf2f(ushort h) {
  union { unsigned u; float f; } v; v.u = ((unsigned)h) << 16; return v.f;
}

// ---------------- setup: params + bf16 weight copies + Lpow table ----------------
__global__ void k_setup(const float* __restrict__ nu_log, const float* __restrict__ theta_log,
                        const float* __restrict__ gamma_log,
                        const float* __restrict__ B_re, const float* __restrict__ B_im,
                        const float* __restrict__ C_re, const float* __restrict__ C_im,
                        float2* __restrict__ Lc, float2* __restrict__ LCH,
                        float2* __restrict__ Lpow,
                        ushort* __restrict__ BnRe, ushort* __restrict__ BnIm,
                        ushort* __restrict__ CRe, ushort* __restrict__ CIm) {
  int bid = blockIdx.x, tid = threadIdx.x;
  if (bid < NN) {
    int m = bid, n = tid;
    float g = expf(gamma_log[m]);
    int idx = m * NN + n;
    BnRe[idx] = f2bf(B_re[idx] * g);
    BnIm[idx] = f2bf(B_im[idx] * g);
    CRe[idx]  = f2bf(C_re[idx]);
    CIm[idx]  = f2bf(-C_im[idx]);   // pre-negated so GEMM2 is pure accumulate
  } else {
    int m = tid;
    float Lmod = expf(-expf(nu_log[m]));
    float th = expf(theta_log[m]);
    float lre = Lmod * cosf(th), lim = Lmod * sinf(th);
    Lc[m] = make_float2(lre, lim);
    float pr = 1.f, pi = 0.f;
    for (int k = 0; k < CH; ++k) {
      // Lpow[t][m] = L^(CH-1-t): weight of Bu[t] in the chunk carry
      Lpow[(size_t)(CH - 1 - k) * NN + m] = make_float2(pr, pi);  // L^k
      float npr = pr * lre - pi * lim;
      pi = pr * lim + pi * lre;
      pr = npr;
    }
    LCH[m] = make_float2(pr, pi);   // L^CH
  }
}

// ---- GEMM1 tile (64 rows x 256 ch) into swizzled packed-u32 LDS (VERBATIM R3) ----
static __device__ __forceinline__ void gemm1_to_lds(const float* __restrict__ x,
                                                    const ushort* __restrict__ BnRe,
                                                    const ushort* __restrict__ BnIm,
                                                    char* lds, int tbase, int tid) {
  int lane = tid & 63, wid = tid >> 6;
  int lr = lane & 15, lg = lane >> 4;
  int mq = wid * 64;

  f4 accRe[4][4], accIm[4][4];
  for (int i = 0; i < 4; ++i)
    for (int j = 0; j < 4; ++j) { accRe[i][j] = (f4)0.f; accIm[i][j] = (f4)0.f; }

  for (int ks = 0; ks < 8; ++ks) {
    int k0 = ks * 32 + lg * 8;
    b8 a[4];
    for (int mf = 0; mf < 4; ++mf) {
      const float* px = x + (size_t)(tbase + mf * 16 + lr) * NN + k0;
      f4 x0 = *(const f4*)px;
      f4 x1 = *(const f4*)(px + 4);
      b8 t;
      t[0] = (short)f2bf(x0[0]); t[1] = (short)f2bf(x0[1]);
      t[2] = (short)f2bf(x0[2]); t[3] = (short)f2bf(x0[3]);
      t[4] = (short)f2bf(x1[0]); t[5] = (short)f2bf(x1[1]);
      t[6] = (short)f2bf(x1[2]); t[7] = (short)f2bf(x1[3]);
      a[mf] = t;
    }
    for (int nf = 0; nf < 4; ++nf) {
      int mrow = mq + nf * 16 + lr;
      b8 br = *(const b8*)(BnRe + (size_t)mrow * NN + k0);
      b8 bi = *(const b8*)(BnIm + (size_t)mrow * NN + k0);
      for (int mf = 0; mf < 4; ++mf) {
        accRe[mf][nf] = __builtin_amdgcn_mfma_f32_16x16x32_bf16(a[mf], br, accRe[mf][nf], 0, 0, 0);
        accIm[mf][nf] = __builtin_amdgcn_mfma_f32_16x16x32_bf16(a[mf], bi, accIm[mf][nf], 0, 0, 0);
      }
    }
  }
  for (int mf = 0; mf < 4; ++mf)
    for (int nf = 0; nf < 4; ++nf)
      for (int r = 0; r < 4; ++r) {
        int row = mf * 16 + lg * 4 + r;
        int col = mq + nf * 16 + lr;
        unsigned p = (unsigned)f2bf(accRe[mf][nf][r]) | ((unsigned)f2bf(accIm[mf][nf][r]) << 16);
        int off = row * 1024 + ((col * 4) ^ ((row & 7) << 4));
        *(unsigned*)(lds + off) = p;
      }
}

// ---------------- K1: GEMM1 in regs -> weighted reduce -> carry (NO LDS) ----
__global__ __launch_bounds__(256) void k_carry(const float* __restrict__ x,
                                               const ushort* __restrict__ BnRe,
                                               const ushort* __restrict__ BnIm,
                                               const float2* __restrict__ Lpow,
                                               float2* __restrict__ carry) {
  int cid = blockIdx.x, tid = threadIdx.x;
  int lane = tid & 63, wid = tid >> 6;
  int lr = lane & 15, lg = lane >> 4;
  int mq = wid * 64;
  int tbase = cid * CH;

  f4 accRe[4][4], accIm[4][4];
  for (int i = 0; i < 4; ++i)
    for (int j = 0; j < 4; ++j) { accRe[i][j] = (f4)0.f; accIm[i][j] = (f4)0.f; }

  for (int ks = 0; ks < 8; ++ks) {        // VERBATIM R3 GEMM1 compute
    int k0 = ks * 32 + lg * 8;
    b8 a[4];
    for (int mf = 0; mf < 4; ++mf) {
      const float* px = x + (size_t)(tbase + mf * 16 + lr) * NN + k0;
      f4 x0 = *(const f4*)px;
      f4 x1 = *(const f4*)(px + 4);
      b8 t;
      t[0] = (short)f2bf(x0[0]); t[1] = (short)f2bf(x0[1]);
      t[2] = (short)f2bf(x0[2]); t[3] = (short)f2bf(x0[3]);
      t[4] = (short)f2bf(x1[0]); t[5] = (short)f2bf(x1[1]);
      t[6] = (short)f2bf(x1[2]); t[7] = (short)f2bf(x1[3]);
      a[mf] = t;
    }
    for (int nf = 0; nf < 4; ++nf) {
      int mrow = mq + nf * 16 + lr;
      b8 br = *(const b8*)(BnRe + (size_t)mrow * NN + k0);
      b8 bi = *(const b8*)(BnIm + (size_t)mrow * NN + k0);
      for (int mf = 0; mf < 4; ++mf) {
        accRe[mf][nf] = __builtin_amdgcn_mfma_f32_16x16x32_bf16(a[mf], br, accRe[mf][nf], 0, 0, 0);
        accIm[mf][nf] = __builtin_amdgcn_mfma_f32_16x16x32_bf16(a[mf], bi, accIm[mf][nf], 0, 0, 0);
      }
    }
  }

  // carry[col] = sum_t L^(63-t) * Bu[t][col], fp32, reduced over the 4 lg-lanes
  for (int nf = 0; nf < 4; ++nf) {
    int col = mq + nf * 16 + lr;
    float sr = 0.f, si = 0.f;
    for (int mf = 0; mf < 4; ++mf)
      for (int q = 0; q < 4; ++q) {
        int t = mf * 16 + lg * 4 + q;
        float2 w = Lpow[(size_t)t * NN + col];
        float br = accRe[mf][nf][q], bi = accIm[mf][nf][q];
        sr += w.x * br - w.y * bi;
        si += w.x * bi + w.y * br;
      }
    sr += __shfl_xor(sr, 16, 64);  si += __shfl_xor(si, 16, 64);
    sr += __shfl_xor(sr, 32, 64);  si += __shfl_xor(si, 32, 64);
    if (lg == 0) carry[(size_t)cid * NN + col] = make_float2(sr, si);
  }
}

// ---------------- K2: scan carries across chunks, in place (VERBATIM R3) ----
__global__ void k_seed(float2* __restrict__ carrySeed, const float2* __restrict__ LCH) {
  int b = blockIdx.x, m = threadIdx.x;
  float2 LC = LCH[m];
  float hr = 0.f, hi = 0.f;
  for (int g = 0; g < GPB; ++g) {
    size_t idx = ((size_t)b * GPB + g) * NN + m;
    float2 c = carrySeed[idx];
    carrySeed[idx] = make_float2(hr, hi);
    float nr = LC.x * hr - LC.y * hi + c.x;
    hi = LC.x * hi + LC.y * hr + c.y;
    hr = nr;
  }
}

// ---------------- K3: recompute GEMM1, seeded scan, GEMM2 (VERBATIM R3) ----
__global__ __launch_bounds__(256) void k_out(const float* __restrict__ x,
                                             const ushort* __restrict__ BnRe,
                                             const ushort* __restrict__ BnIm,
                                             const float2* __restrict__ Lc,
                                             const float2* __restrict__ seed,
                                             const ushort* __restrict__ CRe,
                                             const ushort* __restrict__ CIm,
                                             float* __restrict__ out) {
  __shared__ char lds[CH * 1024];
  int cid = blockIdx.x, tid = threadIdx.x;
  size_t rowbase = (size_t)cid * CH;
  gemm1_to_lds(x, BnRe, BnIm, lds, cid * CH, tid);
  __syncthreads();

  { // seeded scan, in place (packed Bu -> packed h, both 2xbf16)
    int c = tid;
    float2 L = Lc[c];
    float2 s = seed[(size_t)cid * NN + c];
    float hr = s.x, hi = s.y;
    for (int k = 0; k < CH; ++k) {
      int off = k * 1024 + ((c * 4) ^ ((k & 7) << 4));
      unsigned u = *(const unsigned*)(lds + off);
      float ur = bf2f((ushort)(u & 0xffffu)), ui = bf2f((ushort)(u >> 16));
      float nr = L.x * hr - L.y * hi + ur;
      hi = L.x * hi + L.y * hr + ui;
      hr = nr;
      *(unsigned*)(lds + off) = (unsigned)f2bf(hr) | ((unsigned)f2bf(hi) << 16);
    }
  }
  __syncthreads();

  // GEMM2: out[t][m] = sum_n hRe[t][n]*CRe[m][n] + hIm[t][n]*(-CIm[m][n])
  int lane = tid & 63, wid = tid >> 6;
  int lr = lane & 15, lg = lane >> 4;
  int mq = wid * 64;
  f4 acc[4][4];
  for (int i = 0; i < 4; ++i)
    for (int j = 0; j < 4; ++j) acc[i][j] = (f4)0.f;

  for (int ks = 0; ks < 8; ++ks) {
    int k0 = ks * 32 + lg * 8;
    b8 ar[4], ai[4];
    for (int mf = 0; mf < 4; ++mf) {
      int row = mf * 16 + lr;
      int m4 = (row & 7) << 4;
      const char* base = lds + row * 1024;
      u4 p0 = *(const u4*)(base + ((k0 * 4) ^ m4));        // channels k0..k0+3 (packed)
      u4 p1 = *(const u4*)(base + ((k0 * 4 + 16) ^ m4));   // channels k0+4..k0+7
      b8 tr, ti;
      tr[0] = (short)(p0[0] & 0xffffu); ti[0] = (short)(p0[0] >> 16);
      tr[1] = (short)(p0[1] & 0xffffu); ti[1] = (short)(p0[1] >> 16);
      tr[2] = (short)(p0[2] & 0xffffu); ti[2] = (short)(p0[2] >> 16);
      tr[3] = (short)(p0[3] & 0xffffu); ti[3] = (short)(p0[3] >> 16);
      tr[4] = (short)(p1[0] & 0xffffu); ti[4] = (short)(p1[0] >> 16);
      tr[5] = (short)(p1[1] & 0xffffu); ti[5] = (short)(p1[1] >> 16);
      tr[6] = (short)(p1[2] & 0xffffu); ti[6] = (short)(p1[2] >> 16);
      tr[7] = (short)(p1[3] & 0xffffu); ti[7] = (short)(p1[3] >> 16);
      ar[mf] = tr; ai[mf] = ti;
    }
    for (int nf = 0; nf < 4; ++nf) {
      int m = mq + nf * 16 + lr;
      b8 cr = *(const b8*)(CRe + (size_t)m * NN + k0);
      b8 ci = *(const b8*)(CIm + (size_t)m * NN + k0);
      for (int mf = 0; mf < 4; ++mf) {
        acc[mf][nf] = __builtin_amdgcn_mfma_f32_16x16x32_bf16(ar[mf], cr, acc[mf][nf], 0, 0, 0);
        acc[mf][nf] = __builtin_amdgcn_mfma_f32_16x16x32_bf16(ai[mf], ci, acc[mf][nf], 0, 0, 0);
      }
    }
  }
  for (int mf = 0; mf < 4; ++mf)
    for (int nf = 0; nf < 4; ++nf)
      for (int r = 0; r < 4; ++r) {
        size_t t = rowbase + mf * 16 + lg * 4 + r;
        out[t * NN + mq + nf * 16 + lr] = acc[mf][nf][r];
      }
}

extern "C" void kernel_launch(void* const* d_in, const int* in_sizes, int n_in,
                              void* d_out, int out_size, void* d_ws, size_t ws_size,
                              hipStream_t stream) {
  const float* x         = (const float*)d_in[0];
  const float* nu_log    = (const float*)d_in[1];
  const float* theta_log = (const float*)d_in[2];
  const float* gamma_log = (const float*)d_in[3];
  const float* B_re      = (const float*)d_in[4];
  const float* B_im      = (const float*)d_in[5];
  const float* C_re      = (const float*)d_in[6];
  const float* C_im      = (const float*)d_in[7];
  float* out = (float*)d_out;

  // d_ws usage: 2,756,608 bytes (R3 layout + Lpow table appended).
  char* ws = (char*)d_ws;
  float2*  carrySeed = (float2*)(ws + 0);        // 1024*256*8 = 2,097,152
  float2*  Lc   = (float2*)(ws + 2097152);       // 2,048
  float2*  LCH  = (float2*)(ws + 2099200);       // 2,048
  ushort*  BnRe = (ushort*)(ws + 2101248);       // 131,072
  ushort*  BnIm = (ushort*)(ws + 2232320);       // 131,072
  ushort*  CRe  = (ushort*)(ws + 2363392);       // 131,072
  ushort*  CIm  = (ushort*)(ws + 2494464);       // 131,072  (end 2,625,536)
  float2*  Lpow = (float2*)(ws + 2625536);       // 64*256*8 = 131,072 (end 2,756,608)

  hipLaunchKernelGGL(k_setup, dim3(NN + 1), dim3(NN), 0, stream,
                     nu_log, theta_log, gamma_log, B_re, B_im, C_re, C_im,
                     Lc, LCH, Lpow, BnRe, BnIm, CRe, CIm);
  hipLaunchKernelGGL(k_carry, dim3(NCHUNK), dim3(256), 0, stream,
                     x, BnRe, BnIm, Lpow, carrySeed);
  hipLaunchKernelGGL(k_seed, dim3(NB), dim3(NN), 0, stream, carrySeed, LCH);
  hipLaunchKernelGGL(k_out, dim3(NCHUNK), dim3(256), 0, stream,
                     x, BnRe, BnIm, Lc, carrySeed, CRe, CIm, out);
}